// Round 2
// 609.649 us; speedup vs baseline: 1.2332x; 1.2332x over previous
//
#include <hip/hip_runtime.h>
#include <hip/hip_bf16.h>

#define FEAT 128
#define BATCH_N 500000

typedef unsigned short u16;
typedef __attribute__((ext_vector_type(8))) short short8;
typedef __attribute__((ext_vector_type(4))) float f32x4;

__device__ __forceinline__ u16 f2bf(float f) {
  union { float f; unsigned u; } cv; cv.f = f;
  unsigned u = cv.u;
  return (u16)((u + 0x7fffu + ((u >> 16) & 1u)) >> 16);  // RNE, inputs never NaN
}

__device__ __forceinline__ float lrelu(float x) { return x > 0.f ? x : 0.2f * x; }

// ---------------- Phase A: M = W_fc @ W_gat (bf16), u = W_gat^T att_src,
// v = W_gat^T att_dst, c = W_fc @ b_gat + b_fc ----------------
__global__ __launch_bounds__(128) void prep_kernel(
    const float* __restrict__ Wg, const float* __restrict__ as_,
    const float* __restrict__ ad_, const float* __restrict__ bg,
    const float* __restrict__ Wf, const float* __restrict__ bf_,
    u16* __restrict__ Mbf, float* __restrict__ u, float* __restrict__ v,
    float* __restrict__ c) {
  const int i = blockIdx.x, k = threadIdx.x;
  float acc = 0.f;
  for (int j = 0; j < FEAT; ++j) acc = fmaf(Wf[i * FEAT + j], Wg[j * FEAT + k], acc);
  Mbf[i * FEAT + k] = f2bf(acc);
  if (i == 0) {
    float uu = 0.f, vv = 0.f;
    for (int j = 0; j < FEAT; ++j) {
      float w = Wg[j * FEAT + k];
      uu = fmaf(as_[j], w, uu);
      vv = fmaf(ad_[j], w, vv);
    }
    u[k] = uu; v[k] = vv;
  } else if (i == 1) {
    float cc = bf_[k];
    for (int j = 0; j < FEAT; ++j) cc = fmaf(Wf[k * FEAT + j], bg[j], cc);
    c[k] = cc;
  }
}

// ---------------- Phase B: attention scalars (IDENTICAL to prior round) +
// MFMA bf16 epilogue: out[64][128] = x @ M^T + c ----------------
__global__ __launch_bounds__(256) void gat_kernel(
    const float* __restrict__ f1, const float* __restrict__ f2,
    const u16* __restrict__ Mbf, const float* __restrict__ u,
    const float* __restrict__ v, const float* __restrict__ c,
    float* __restrict__ out) {
  __shared__ __align__(16) u16 M_lds[128 * 136];
  __shared__ __align__(16) u16 x_lds[64 * 136];

  const int tid = threadIdx.x;
  const int lane = tid & 63;
  const int wave = tid >> 6;
  const int k4 = lane & 31;   // float4 index within a row (dot phase)
  const int hlf = lane >> 5;  // which of 2 rows this lane reduces

  // stage M into LDS: 2048 x 16B chunks, 8 per thread, coalesced
  const uint4* Ms = reinterpret_cast<const uint4*>(Mbf);
#pragma unroll
  for (int it = 0; it < 8; ++it) {
    int g = it * 256 + tid;
    int n = g >> 4, kc = (g & 15) << 3;
    *reinterpret_cast<uint4*>(&M_lds[n * 136 + kc]) = Ms[g];
  }

  const float4 uvec = reinterpret_cast<const float4*>(u)[k4];
  const float4 vvec = reinterpret_cast<const float4*>(v)[k4];

  // hoist bias loads (lane-dependent, L2-resident) so latency hides under
  // the attention phase
  const int lr = lane & 15;  // MFMA A-row / B-row (out col) within tile
  const int lk = lane >> 4;  // MFMA k-octet (0..3)
  float creg[8];
#pragma unroll
  for (int ct = 0; ct < 8; ++ct) creg[ct] = c[ct * 16 + lr];

  __syncthreads();

  const int rbase = blockIdx.x * 64 + wave * 16;
  const bool active = rbase < BATCH_N;  // 500000 % 16 == 0 -> all-or-nothing per wave

  if (active) {
    const float4* f1p = reinterpret_cast<const float4*>(f1) + (size_t)rbase * 32;
    const float4* f2p = reinterpret_cast<const float4*>(f2) + (size_t)rbase * 32;
    float4 nf1 = f1p[hlf * 32 + k4];
    float4 nf2 = f2p[hlf * 32 + k4];
#pragma unroll
    for (int it = 0; it < 8; ++it) {
      float4 a1 = nf1, a2 = nf2;
      if (it < 7) {  // prefetch next pair before the reduction chain
        int o = (it * 2 + 2 + hlf) * 32 + k4;
        nf1 = f1p[o];
        nf2 = f2p[o];
      }
      float d1s = a1.x * uvec.x + a1.y * uvec.y + a1.z * uvec.z + a1.w * uvec.w;
      float d1d = a1.x * vvec.x + a1.y * vvec.y + a1.z * vvec.z + a1.w * vvec.w;
      float d2s = a2.x * uvec.x + a2.y * uvec.y + a2.z * uvec.z + a2.w * uvec.w;
      float d2d = a2.x * vvec.x + a2.y * vvec.y + a2.z * vvec.z + a2.w * vvec.w;
#pragma unroll
      for (int m = 1; m <= 16; m <<= 1) {
        d1s += __shfl_xor(d1s, m, 64);
        d1d += __shfl_xor(d1d, m, 64);
        d2s += __shfl_xor(d2s, m, 64);
        d2d += __shfl_xor(d2d, m, 64);
      }
      // dst node 0: edges 1->0, 0->0 ; dst node 1: edges 0->1, 1->1
      float e10 = lrelu(d2s + d1d);
      float e00 = lrelu(d1s + d1d);
      float mx0 = fmaxf(e10, e00);
      float p10 = __expf(e10 - mx0), p00 = __expf(e00 - mx0);
      float inv0 = 1.0f / (p10 + p00);
      float e01 = lrelu(d1s + d2d);
      float e11 = lrelu(d2s + d2d);
      float mx1 = fmaxf(e01, e11);
      float p01 = __expf(e01 - mx1), p11 = __expf(e11 - mx1);
      float inv1 = 1.0f / (p01 + p11);
      float alpha = 0.5f * (p00 * inv0 + p01 * inv1);  // coeff of H1/f1
      float beta  = 0.5f * (p10 * inv0 + p11 * inv1);  // coeff of H2/f2
      ushort4 xw;
      xw.x = f2bf(alpha * a1.x + beta * a2.x);
      xw.y = f2bf(alpha * a1.y + beta * a2.y);
      xw.z = f2bf(alpha * a1.z + beta * a2.z);
      xw.w = f2bf(alpha * a1.w + beta * a2.w);
      int xrow = wave * 16 + it * 2 + hlf;
      *reinterpret_cast<ushort4*>(&x_lds[xrow * 136 + k4 * 4]) = xw;
    }
  }

  __syncthreads();  // all threads reach this (no early return)

  // ---------- MFMA epilogue: out[64][128] = x @ M^T + c ----------
  // Wave w owns row-tile w (16 samples). Fragment layout (verified m89/m91):
  //   A: lane -> x[wave*16 + (lane&15)][(lane>>4)*8 + j], j=0..7 contiguous
  //   B: lane -> M[ct*16 + (lane&15)][(lane>>4)*8 + j]   (B = M^T GEMM)
  //   D: col = lane&15, row = (lane>>4)*4 + reg
  // All LDS frag reads are 16B-aligned ds_read_b128, 2-way bank alias (free).
  short8 afr[4];
#pragma unroll
  for (int kk = 0; kk < 4; ++kk)
    afr[kk] = *reinterpret_cast<const short8*>(
        &x_lds[(wave * 16 + lr) * 136 + kk * 32 + lk * 8]);

  const int rowbase = blockIdx.x * 64 + wave * 16 + lk * 4;
#pragma unroll
  for (int ct = 0; ct < 8; ++ct) {
    f32x4 acc = {0.f, 0.f, 0.f, 0.f};
#pragma unroll
    for (int kk = 0; kk < 4; ++kk) {
      short8 bfr = *reinterpret_cast<const short8*>(
          &M_lds[(ct * 16 + lr) * 136 + kk * 32 + lk * 8]);
      acc = __builtin_amdgcn_mfma_f32_16x16x32_bf16(afr[kk], bfr, acc, 0, 0, 0);
    }
    const int gcol = ct * 16 + lr;
    const float cj = creg[ct];
#pragma unroll
    for (int r = 0; r < 4; ++r) {
      const int grow = rowbase + r;
      if (grow < BATCH_N) out[(size_t)grow * 128 + gcol] = acc[r] + cj;
    }
  }
}

extern "C" void kernel_launch(void* const* d_in, const int* in_sizes, int n_in,
                              void* d_out, int out_size, void* d_ws, size_t ws_size,
                              hipStream_t stream) {
  const float* f1 = (const float*)d_in[0];
  const float* f2 = (const float*)d_in[1];
  const float* Wg = (const float*)d_in[2];
  const float* as_ = (const float*)d_in[3];
  const float* ad_ = (const float*)d_in[4];
  const float* bg = (const float*)d_in[5];
  const float* Wf = (const float*)d_in[6];
  const float* bf_ = (const float*)d_in[7];
  float* out = (float*)d_out;

  u16* Mbf = (u16*)d_ws;                              // 128*128 bf16 = 32768 B
  float* u = (float*)((char*)d_ws + 32768);           // 512 B
  float* v = u + 128;                                 // 512 B
  float* c = v + 128;                                 // 512 B

  prep_kernel<<<dim3(128), dim3(128), 0, stream>>>(Wg, as_, ad_, bg, Wf, bf_, Mbf, u, v, c);
  const int nblocks = (BATCH_N + 63) / 64;  // 7813
  gat_kernel<<<dim3(nblocks), dim3(256), 0, stream>>>(f1, f2, Mbf, u, v, c, out);
}